// Round 2
// baseline (163.291 us; speedup 1.0000x reference)
//
#include <hip/hip_runtime.h>
#include <hip/hip_fp16.h>

#define NNODES 100000
#define KNBR 32
#define IN_C 128
#define OUT_C 64

// ======================= Kernel 1: h = x @ W^T (fp32 compute, fp16 store) ==
// Block 256 threads; tile = 64 nodes x 64 channels; K chunked by 64.
// LDS holds transposed (k-major) tiles so compute reads are ds_read_b128.
__global__ __launch_bounds__(256) void gemm_h_kernel(
    const float* __restrict__ x, const float* __restrict__ W,
    __half* __restrict__ h)
{
    // stride 68 floats: keeps 16B alignment for float4 reads (68*4=272=16*17)
    // and rotates banks by 4 per row (staging-write conflicts only ~8-way on
    // the 6%-of-traffic staging path; compute reads are 2-way = free).
    __shared__ __align__(16) float sx[64 * 68];
    __shared__ __align__(16) float sw[64 * 68];

    const int t = threadIdx.x;
    const int node0 = blockIdx.x * 64;
    const int tx = t & 15;   // channel quad: channels 4*tx..4*tx+3
    const int ty = t >> 4;   // node quad:    nodes    4*ty..4*ty+3
    const int kq = t & 15;   // staging k-quad
    const int sl = t >> 4;   // staging row base

    float acc[4][4];
#pragma unroll
    for (int i = 0; i < 4; ++i)
#pragma unroll
        for (int j = 0; j < 4; ++j) acc[i][j] = 0.f;

    for (int kc = 0; kc < 2; ++kc) {
        const int kbase = kc * 64;
        __syncthreads();
#pragma unroll
        for (int pass = 0; pass < 4; ++pass) {
            const int nl = sl + pass * 16;           // 0..63
            int nn = node0 + nl;
            if (nn > NNODES - 1) nn = NNODES - 1;    // clamp tail reads
            const float4 xv = *(const float4*)(x + nn * IN_C + kbase + 4 * kq);
            sx[(4 * kq + 0) * 68 + nl] = xv.x;
            sx[(4 * kq + 1) * 68 + nl] = xv.y;
            sx[(4 * kq + 2) * 68 + nl] = xv.z;
            sx[(4 * kq + 3) * 68 + nl] = xv.w;
            const float4 wv = *(const float4*)(W + nl * IN_C + kbase + 4 * kq);
            sw[(4 * kq + 0) * 68 + nl] = wv.x;
            sw[(4 * kq + 1) * 68 + nl] = wv.y;
            sw[(4 * kq + 2) * 68 + nl] = wv.z;
            sw[(4 * kq + 3) * 68 + nl] = wv.w;
        }
        __syncthreads();
#pragma unroll 8
        for (int kk = 0; kk < 64; ++kk) {
            const float4 wv = *(const float4*)&sw[kk * 68 + 4 * tx];
            const float4 xv = *(const float4*)&sx[kk * 68 + 4 * ty];
            acc[0][0] += xv.x * wv.x; acc[0][1] += xv.x * wv.y;
            acc[0][2] += xv.x * wv.z; acc[0][3] += xv.x * wv.w;
            acc[1][0] += xv.y * wv.x; acc[1][1] += xv.y * wv.y;
            acc[1][2] += xv.y * wv.z; acc[1][3] += xv.y * wv.w;
            acc[2][0] += xv.z * wv.x; acc[2][1] += xv.z * wv.y;
            acc[2][2] += xv.z * wv.z; acc[2][3] += xv.z * wv.w;
            acc[3][0] += xv.w * wv.x; acc[3][1] += xv.w * wv.y;
            acc[3][2] += xv.w * wv.z; acc[3][3] += xv.w * wv.w;
        }
    }
#pragma unroll
    for (int i = 0; i < 4; ++i) {
        const int node = node0 + 4 * ty + i;
        if (node < NNODES) {
            __half2 p0 = __floats2half2_rn(acc[i][0], acc[i][1]);
            __half2 p1 = __floats2half2_rn(acc[i][2], acc[i][3]);
            uint2 st;
            st.x = *(unsigned int*)&p0;
            st.y = *(unsigned int*)&p1;
            *(uint2*)(h + node * OUT_C + 4 * tx) = st;
        }
    }
}

// ======================= Kernel 2: gather + rank-15-of-32 ==================
// Packed half2 min/max via gfx950 VOP3P — ROCm 7.2 headers lack __hmin2/__hmax2.
__device__ __forceinline__ unsigned pk_min(unsigned a, unsigned b) {
    unsigned d;
    asm("v_pk_min_f16 %0, %1, %2" : "=v"(d) : "v"(a), "v"(b));
    return d;
}
__device__ __forceinline__ unsigned pk_max(unsigned a, unsigned b) {
    unsigned d;
    asm("v_pk_max_f16 %0, %1, %2" : "=v"(d) : "v"(a), "v"(b));
    return d;
}
__device__ __forceinline__ void ce(unsigned& a, unsigned& b) {
    const unsigned lo = pk_min(a, b);
    b = pk_max(a, b);
    a = lo;
}

// Batcher odd-even mergesort, n=16, 63 comparators (hardcoded list).
__device__ __forceinline__ void sort16(unsigned* v) {
    constexpr unsigned char net[63][2] = {
        {0,1},{2,3},{4,5},{6,7},{8,9},{10,11},{12,13},{14,15},
        {0,2},{1,3},{4,6},{5,7},{8,10},{9,11},{12,14},{13,15},
        {1,2},{5,6},{9,10},{13,14},
        {0,4},{1,5},{2,6},{3,7},{8,12},{9,13},{10,14},{11,15},
        {2,4},{3,5},{10,12},{11,13},
        {1,2},{3,4},{5,6},{9,10},{11,12},{13,14},
        {0,8},{1,9},{2,10},{3,11},{4,12},{5,13},{6,14},{7,15},
        {4,8},{5,9},{6,10},{7,11},
        {2,4},{3,5},{6,8},{7,9},{10,12},{11,13},
        {1,2},{3,4},{5,6},{7,8},{9,10},{11,12},{13,14}
    };
#pragma unroll
    for (int i = 0; i < 63; ++i) ce(v[net[i][0]], v[net[i][1]]);
}

// rank 15 (0-indexed) of 32 values: sort both 16-halves, then a pruned
// Batcher odd-even merge that materializes only output 15.
// out15 = min(E[8], O[7]) of the even/odd sub-merges, expanded recursively.
__device__ __forceinline__ unsigned median32(unsigned* v) {
    sort16(v);
    sort16(v + 16);
    const unsigned* A = v;
    const unsigned* B = v + 16;
    // E-side (needs out[8] of merge of even-indexed elements)
    const unsigned e2a = pk_max(pk_max(A[0], B[0]), pk_min(A[8],  B[8]));
    const unsigned o1a = pk_min(pk_max(A[4], B[4]), pk_min(A[12], B[12]));
    const unsigned Ep4 = pk_max(e2a, o1a);
    const unsigned e2b = pk_max(pk_max(A[2], B[2]), pk_min(A[10], B[10]));
    const unsigned o1b = pk_min(pk_max(A[6], B[6]), pk_min(A[14], B[14]));
    const unsigned Op3 = pk_min(e2b, o1b);
    const unsigned E8  = pk_max(Ep4, Op3);
    // O-side (needs out[7] of merge of odd-indexed elements)
    const unsigned e2c = pk_max(pk_max(A[1], B[1]), pk_min(A[9],  B[9]));
    const unsigned o1c = pk_min(pk_max(A[5], B[5]), pk_min(A[13], B[13]));
    const unsigned Ep4o = pk_max(e2c, o1c);
    const unsigned e2d = pk_max(pk_max(A[3], B[3]), pk_min(A[11], B[11]));
    const unsigned o1d = pk_min(pk_max(A[7], B[7]), pk_min(A[15], B[15]));
    const unsigned Op3o = pk_min(e2d, o1d);
    const unsigned O7  = pk_min(Ep4o, Op3o);
    return pk_min(E8, O7);
}

// 16 lanes per node; each lane owns 4 channels as two packed-half2 streams.
// Block 256 threads = 16 nodes. Row indices broadcast within the 16-lane
// group via __shfl(width=16) (wave-uniform per group -> one 128B gather/row).
__global__ __launch_bounds__(256) void median_kernel(
    const __half* __restrict__ h, const int* __restrict__ nbrs,
    float* __restrict__ out)
{
    const int t = threadIdx.x;
    const int li = t & 15;
    const int node = blockIdx.x * 16 + (t >> 4);
    const int ch0 = 4 * li;

    const int ia = nbrs[node * KNBR + li];
    const int ib = nbrs[node * KNBR + 16 + li];

    unsigned a[KNBR];  // channels ch0, ch0+1
    unsigned b[KNBR];  // channels ch0+2, ch0+3
#pragma unroll
    for (int k = 0; k < KNBR; ++k) {
        const int row = (k < 16) ? __shfl(ia, k, 16) : __shfl(ib, k - 16, 16);
        const uint2 rv = *(const uint2*)(h + row * OUT_C + ch0);
        a[k] = rv.x;
        b[k] = rv.y;
    }

    const unsigned ma = median32(a);
    const unsigned mb = median32(b);
    const __half2 ha = *(const __half2*)&ma;
    const __half2 hb = *(const __half2*)&mb;

    float4 o;
    o.x = __low2float(ha);
    o.y = __high2float(ha);
    o.z = __low2float(hb);
    o.w = __high2float(hb);
    *(float4*)(out + node * OUT_C + ch0) = o;
}

extern "C" void kernel_launch(void* const* d_in, const int* in_sizes, int n_in,
                              void* d_out, int out_size, void* d_ws, size_t ws_size,
                              hipStream_t stream) {
    (void)in_sizes; (void)n_in; (void)out_size; (void)ws_size;
    const float* x    = (const float*)d_in[0];
    const int*   nbrs = (const int*)d_in[1];
    const float* W    = (const float*)d_in[2];
    float* out = (float*)d_out;
    __half* h  = (__half*)d_ws;   // 100000*64*2 = 12.8 MB scratch

    gemm_h_kernel<<<(NNODES + 63) / 64, 256, 0, stream>>>(x, W, h);
    median_kernel<<<NNODES / 16, 256, 0, stream>>>(h, nbrs, out);
}